// Round 13
// baseline (143.055 us; speedup 1.0000x reference)
//
#include <hip/hip_runtime.h>
#include <math.h>

// B=4, H=256, W=256, 100 iters. Closed-form mu-only update (sigma/rou are
// dead code for the mu output):
//   dmu = 2*uw1*mu + uw2*y + ew0*dn + ew1*rt + ew0_up*up + ew1_lf*lf
// Round 21: fold init kernel into tile launch 0. r12 budget: VALU ~30us
// (pk-proven), launches 7x(load+store+gap)~49, prolog ~5-7 (init kernel
// writes 24B/px that launch 0 re-reads = ~45MB round trip + a gap).
// When first: read raw y/ew/uw over the halo tile, build c1 in regs,
// iterate as usual, write c1 interior in the epilogue (interiors tile the
// grid -> full coverage; kernel boundary orders c1 writes before launch 1
// reads). Also: k2x0 extra c1 load retired -- stage k1[3].z in buf[0]'s
// UNUSED scratch row r0+1 (only boundary rows r0/r0+3 are live; iteration
// writes never touch r0+1), read neighbor strip's slot after the staging
// barrier; rg==0 clamps to own k1[0].z (same as r12 row-0 clamp).
// Iteration core identical to r12 (133.5us): 64x64 tile, lane=col, DPP
// laterals, packed v_pk_{fma,mul,add}_f32 pairs (0,3)+(1,2) (no pk
// max/min on gfx950 -> scalar med3 clamp), LDS boundary rows only,
// strip row gate, schedule {16x6, 4}, skip-last-barrier.
#define NPIX  262144
#define TILE  64
#define TS    65             // padded LDS row stride (floats)
#define RPT   4
#define NSTRIP 16            // 16 strips x 4 rows
#define NTHR  1024
#define HALO  16

typedef float v2f __attribute__((ext_vector_type(2)));

__device__ __forceinline__ v2f pk_fma(v2f a, v2f b, v2f c) {
    v2f d;
    asm("v_pk_fma_f32 %0, %1, %2, %3" : "=v"(d) : "v"(a), "v"(b), "v"(c));
    return d;
}
__device__ __forceinline__ v2f pk_mul(v2f a, v2f b) {
    v2f d;
    asm("v_pk_mul_f32 %0, %1, %2" : "=v"(d) : "v"(a), "v"(b));
    return d;
}
__device__ __forceinline__ v2f pk_add(v2f a, v2f b) {
    v2f d;
    asm("v_pk_add_f32 %0, %1, %2" : "=v"(d) : "v"(a), "v"(b));
    return d;
}
__device__ __forceinline__ v2f pk_clamp(v2f a) {   // no pk_max/min on gfx950
    v2f d;
    d.x = fminf(fmaxf(a.x, 0.f), 63.f);   // -> v_med3_f32
    d.y = fminf(fmaxf(a.y, 0.f), 63.f);
    return d;
}
// wave-wide lateral shifts on the VALU pipe (gfx9 DPP, valid on CDNA)
__device__ __forceinline__ float dpp_shr1(float x) {   // lane l <- lane l-1
    int i = __builtin_amdgcn_update_dpp(0, __float_as_int(x),
                                        0x138, 0xf, 0xf, false);
    return __int_as_float(i);
}
__device__ __forceinline__ float dpp_shl1(float x) {   // lane l <- lane l+1
    int i = __builtin_amdgcn_update_dpp(0, __float_as_int(x),
                                        0x130, 0xf, 0xf, false);
    return __int_as_float(i);
}

// c1 = {2*uw1, uw2*y, ew0(down-edge), ew1(right-edge)}.
__global__ __launch_bounds__(NTHR) void tile_kernel(
    const float2* __restrict__ muvI, float2* __restrict__ muvO,
    const float*  __restrict__ yIn,
    const float2* __restrict__ ewIn,
    const float2* __restrict__ uwIn,
    float4* __restrict__ c1,      // read when !first; interior written when first
    float* __restrict__ mu_out,   // non-null on last launch (muv not stored)
    int Tl,                       // iterations this launch (16 or 4)
    int first)                    // launch 0: raw inputs, v=0, writes c1
{
    __shared__ float buf[2][TILE*TS];   // 33.3 KB

    int tid  = threadIdx.x;
    int rg   = tid >> 6;          // wave index == strip index (rows 4rg..+3)
    int lane = tid & 63;          // == tile col
    int bz = blockIdx.z;
    int h0 = blockIdx.y * 32;
    int w0 = blockIdx.x * 32;
    int w  = (w0 + lane - HALO) & 255;
    int r0 = RPT*rg;

    float mu[RPT], v[RPT];
    float4 k1[RPT];
    int gi[RPT];

    // ---- load (fully coalesced) ----
    if (first) {
#pragma unroll
        for (int k = 0; k < RPT; ++k) {
            int h = (h0 + r0 + k - HALO) & 255;
            gi[k] = (bz << 16) | (h << 8) | w;
            float  yv = yIn[gi[k]];
            float2 e  = ewIn[gi[k]];
            float2 u  = uwIn[gi[k]];
            mu[k] = yv;
            v[k]  = 0.f;
            k1[k] = make_float4(2.f*u.x, u.y*yv, e.x, e.y);
        }
    } else {
#pragma unroll
        for (int k = 0; k < RPT; ++k) {
            int h = (h0 + r0 + k - HALO) & 255;
            gi[k] = (bz << 16) | (h << 8) | w;
            float2 s = muvI[gi[k]];
            mu[k] = s.x;
            v[k]  = s.y;
            k1[k] = c1[gi[k]];
        }
    }

    // stage boundary mu rows + k1[3].z scratch (row r0+1 is never live)
    buf[0][r0*TS + lane]       = mu[0];
    buf[0][(r0 + 3)*TS + lane] = mu[3];
    buf[0][(r0 + 1)*TS + lane] = k1[3].z;   // for strip rg+1's k2x0
    __syncthreads();
    float k2x0 = (rg == 0) ? k1[0].z : buf[0][(r0 - 3)*TS + lane];

    // ---- pack state + coefficients: pair A = rows (0,3), B = rows (1,2) ----
    v2f pmA = {mu[0], mu[3]}, pmB = {mu[1], mu[2]};
    v2f pvA = {v[0],  v[3]},  pvB = {v[1],  v[2]};
    v2f KxA = {k1[0].x, k1[3].x}, KxB = {k1[1].x, k1[2].x};
    v2f KyA = {k1[0].y, k1[3].y}, KyB = {k1[1].y, k1[2].y};
    v2f KzA = {k1[0].z, k1[3].z}, KzB = {k1[1].z, k1[2].z};
    v2f KwA = {k1[0].w, k1[3].w}, KwB = {k1[1].w, k1[2].w};
    v2f K2xA = {k2x0,    k1[2].z}, K2xB = {k1[0].z, k1[1].z};
    v2f K2yA = {dpp_shr1(k1[0].w), dpp_shr1(k1[3].w)};
    v2f K2yB = {dpp_shr1(k1[1].w), dpp_shr1(k1[2].w)};
    const v2f C07  = {0.7f, 0.7f};
    const v2f C001 = {0.01f, 0.01f};

    int rm1 = (rg == 0)        ? 0      : r0-1;
    int rp4 = (rg == NSTRIP-1) ? TILE-1 : r0+4;

    // ---- Tl fused Jacobi iterations, one barrier each, strip row gate ----
    for (int s = 0; s < Tl; ++s) {
        const float* __restrict__ cur = buf[s & 1];
        float*       __restrict__ nxt = buf[(s & 1) ^ 1];
        // useful rows [17-Tl+s, 46+Tl-s]; strip granular
        int lo = 14 - Tl + s;                    // 4rg >= lo
        int rgLo = (lo <= 0) ? 0 : ((lo + 3) >> 2);
        int rgHi = (46 + Tl - s) >> 2;           // <= 15 for Tl<=16
        if (rg >= rgLo && rg <= rgHi) {          // wave-uniform branch
            float up0 = cur[rm1*TS + lane];
            float dnL = cur[rp4*TS + lane];
            // pair A (rows 0,3): produces next phase's boundary rows
            v2f upA = {up0,   pmB.y};            // {up(row0), mu2}
            v2f dnA = {pmB.x, dnL};              // {mu1, dn(row3)}
            v2f lfA = {dpp_shr1(pmA.x), dpp_shr1(pmA.y)};
            v2f rtA = {dpp_shl1(pmA.x), dpp_shl1(pmA.y)};
            v2f d = pk_fma(KxA, pmA, KyA);
            d = pk_fma(KzA, dnA, d);
            d = pk_fma(KwA, rtA, d);
            d = pk_fma(K2xA, upA, d);
            d = pk_fma(K2yA, lfA, d);
            pvA = pk_fma(pvA, C07, pk_mul(C001, d));
            v2f nmA = pk_clamp(pk_add(pmA, pvA));
            nxt[r0*TS + lane]       = nmA.x;     // boundary rows out ASAP
            nxt[(r0 + 3)*TS + lane] = nmA.y;
            // pair B (rows 1,2): pure register (old pmA/pmB still live)
            v2f upB = {pmA.x, pmB.x};            // {mu0, mu1}
            v2f dnB = {pmB.y, pmA.y};            // {mu2, mu3}
            v2f lfB = {dpp_shr1(pmB.x), dpp_shr1(pmB.y)};
            v2f rtB = {dpp_shl1(pmB.x), dpp_shl1(pmB.y)};
            v2f e = pk_fma(KxB, pmB, KyB);
            e = pk_fma(KzB, dnB, e);
            e = pk_fma(KwB, rtB, e);
            e = pk_fma(K2xB, upB, e);
            e = pk_fma(K2yB, lfB, e);
            pvB = pk_fma(pvB, C07, pk_mul(C001, e));
            v2f nmB = pk_clamp(pk_add(pmB, pvB));
            pmA = nmA;
            pmB = nmB;
        }
        if (s + 1 < Tl) __syncthreads();   // last phase feeds registers only
    }

    // ---- store interior (rows [16,48), cols [16,48)) ----
    if (lane >= HALO && lane < HALO+32) {
        float muO[RPT] = {pmA.x, pmB.x, pmB.y, pmA.y};
        float vO_[RPT] = {pvA.x, pvB.x, pvB.y, pvA.y};
#pragma unroll
        for (int k = 0; k < RPT; ++k) {
            int r = r0 + k;
            if (r >= HALO && r < HALO+32) {
                if (mu_out) {
                    mu_out[gi[k]] = muO[k];  // final launch: only mu needed
                } else {
                    muvO[gi[k]] = make_float2(muO[k], vO_[k]);
                    if (first) c1[gi[k]] = k1[k];   // build c1 plane once
                }
            }
        }
    }
}

extern "C" void kernel_launch(void* const* d_in, const int* in_sizes, int n_in,
                              void* d_out, int out_size, void* d_ws, size_t ws_size,
                              hipStream_t stream) {
    const float* y  = (const float*)d_in[0];
    const float* ew = (const float*)d_in[1];
    const float* uw = (const float*)d_in[2];
    float* out = (float*)d_out;
    const int N = NPIX;

    // workspace: c1 (float4) + muvA, muvB (float2 planes) = 8 MB
    float4* c1   = (float4*)d_ws;
    float2* muvA = (float2*)(c1 + N);
    float2* muvB = muvA + N;

    // 7 launches: {16 x 6, 4}; launch 0 reads raw inputs and writes c1
    static const int Tls[7] = {16, 16, 16, 16, 16, 16, 4};
    float2 *muvI = muvA, *muvO = muvB;
    for (int l = 0; l < 7; ++l) {
        float* mo = (l == 6) ? out : nullptr;
        hipLaunchKernelGGL(tile_kernel, dim3(8, 8, 4), dim3(NTHR), 0, stream,
                           muvI, muvO, y, (const float2*)ew, (const float2*)uw,
                           c1, mo, Tls[l], (l == 0) ? 1 : 0);
        float2* t = muvI; muvI = muvO; muvO = t;
    }
}

// Round 14
// 140.740 us; speedup vs baseline: 1.0164x; 1.0164x over previous
//
#include <hip/hip_runtime.h>
#include <math.h>

// B=4, H=256, W=256, 100 iters. Closed-form mu-only update (sigma/rou are
// dead code for the mu output):
//   dmu = 2*uw1*mu + uw2*y + ew0*dn + ew1*rt + ew0_up*up + ew1_lf*lf
// Round 22: revert r21's init-fold (regressed: dual-path load bloat; the
// separate init kernel costs ~2us, not 6). Base = r12 (133.5us) + micros:
// (a) balanced schedule {15,15,14,14,14,14,14} (-2.6% gated row-steps vs
// {16x6,4}); (b) skip loads for rows outside the launch's initial read-set
// [16-Tl, 47+Tl] (zeros; garbage-region by the gate argument); (c) iterate
// as {issue up/dn ds_reads -> pair B (LDS-free) -> pair A -> write} so B's
// VALU hides the ds_read latency. Core unchanged: 64x64 tile, lane=col,
// DPP laterals, packed v_pk_{fma,mul,add}_f32 pairs (0,3)+(1,2) (no
// pk_max/min on gfx950 -> scalar med3 clamp), LDS boundary rows only,
// strip row gate [17-Tl+s, 46+Tl-s], skip-last-barrier.
// Budget (r6..r13 fits): 7 x ~6us/launch all-in (launch count floor: RPT=4
// is the unique 256-block geometry; T<=16 is the 64-lane col-halo cap),
// ~30us VALU+DS work, ~30us barrier-chain (path-bound per r10), ~4 prolog.
#define NPIX  262144
#define TILE  64
#define TS    65             // padded LDS row stride (floats)
#define RPT   4
#define NSTRIP 16            // 16 strips x 4 rows
#define NTHR  1024
#define HALO  16

typedef float v2f __attribute__((ext_vector_type(2)));

__device__ __forceinline__ v2f pk_fma(v2f a, v2f b, v2f c) {
    v2f d;
    asm("v_pk_fma_f32 %0, %1, %2, %3" : "=v"(d) : "v"(a), "v"(b), "v"(c));
    return d;
}
__device__ __forceinline__ v2f pk_mul(v2f a, v2f b) {
    v2f d;
    asm("v_pk_mul_f32 %0, %1, %2" : "=v"(d) : "v"(a), "v"(b));
    return d;
}
__device__ __forceinline__ v2f pk_add(v2f a, v2f b) {
    v2f d;
    asm("v_pk_add_f32 %0, %1, %2" : "=v"(d) : "v"(a), "v"(b));
    return d;
}
__device__ __forceinline__ v2f pk_clamp(v2f a) {   // no pk_max/min on gfx950
    v2f d;
    d.x = fminf(fmaxf(a.x, 0.f), 63.f);   // -> v_med3_f32
    d.y = fminf(fmaxf(a.y, 0.f), 63.f);
    return d;
}
// wave-wide lateral shifts on the VALU pipe (gfx9 DPP, valid on CDNA)
__device__ __forceinline__ float dpp_shr1(float x) {   // lane l <- lane l-1
    int i = __builtin_amdgcn_update_dpp(0, __float_as_int(x),
                                        0x138, 0xf, 0xf, false);
    return __int_as_float(i);
}
__device__ __forceinline__ float dpp_shl1(float x) {   // lane l <- lane l+1
    int i = __builtin_amdgcn_update_dpp(0, __float_as_int(x),
                                        0x130, 0xf, 0xf, false);
    return __int_as_float(i);
}

// c1 = {2*uw1, uw2*y, ew0(down-edge), ew1(right-edge)}.
__global__ __launch_bounds__(NTHR) void tile_kernel(
    const float2* __restrict__ muvI, float2* __restrict__ muvO,
    const float4* __restrict__ c1,
    float* __restrict__ mu_out,   // non-null on last launch (muv not stored)
    int Tl,                       // iterations this launch (<= 16)
    int first)                    // launch 0: v := 0
{
    __shared__ float buf[2][TILE*TS];   // 33.3 KB

    int tid  = threadIdx.x;
    int rg   = tid >> 6;          // wave index == strip index (rows 4rg..+3)
    int lane = tid & 63;          // == tile col
    int bz = blockIdx.z;
    int h0 = blockIdx.y * 32;
    int w0 = blockIdx.x * 32;
    int w  = (w0 + lane - HALO) & 255;
    int r0 = RPT*rg;

    float mu[RPT], v[RPT];
    float4 k1[RPT];
    int gi[RPT];

    // ---- load (fully coalesced): muv b64, c1 b128; skip rows outside the
    //      initial read-set [16-Tl, 47+Tl] (garbage-region by gate) ----
#pragma unroll
    for (int k = 0; k < RPT; ++k) {
        int r = r0 + k;
        int h = (h0 + r - HALO) & 255;
        gi[k] = (bz << 16) | (h << 8) | w;
        if (r >= 16 - Tl && r <= 47 + Tl) {
            float2 s = muvI[gi[k]];
            mu[k] = s.x;
            v[k]  = first ? 0.f : s.y;
            k1[k] = c1[gi[k]];
        } else {
            mu[k] = 0.f; v[k] = 0.f;
            k1[k] = make_float4(0.f, 0.f, 0.f, 0.f);
        }
    }
    float k2x0;
    {
        int hu = (h0 + ((rg == 0) ? 0 : r0-1) - HALO) & 255;
        k2x0 = c1[(bz << 16) | (hu << 8) | w].z;   // up-nb ew0 for row 0
    }

    // ---- pack state + coefficients: pair A = rows (0,3), B = rows (1,2) ----
    v2f pmA = {mu[0], mu[3]}, pmB = {mu[1], mu[2]};
    v2f pvA = {v[0],  v[3]},  pvB = {v[1],  v[2]};
    v2f KxA = {k1[0].x, k1[3].x}, KxB = {k1[1].x, k1[2].x};
    v2f KyA = {k1[0].y, k1[3].y}, KyB = {k1[1].y, k1[2].y};
    v2f KzA = {k1[0].z, k1[3].z}, KzB = {k1[1].z, k1[2].z};
    v2f KwA = {k1[0].w, k1[3].w}, KwB = {k1[1].w, k1[2].w};
    v2f K2xA = {k2x0,    k1[2].z}, K2xB = {k1[0].z, k1[1].z};
    v2f K2yA = {dpp_shr1(k1[0].w), dpp_shr1(k1[3].w)};
    v2f K2yB = {dpp_shr1(k1[1].w), dpp_shr1(k1[2].w)};
    const v2f C07  = {0.7f, 0.7f};
    const v2f C001 = {0.01f, 0.01f};

    // stage only strip-boundary rows (the only LDS-read rows)
    buf[0][r0*TS + lane]       = pmA.x;
    buf[0][(r0 + 3)*TS + lane] = pmA.y;
    __syncthreads();

    int rm1 = (rg == 0)        ? 0      : r0-1;
    int rp4 = (rg == NSTRIP-1) ? TILE-1 : r0+4;

    // ---- Tl fused Jacobi iterations, one barrier each, strip row gate ----
    for (int s = 0; s < Tl; ++s) {
        const float* __restrict__ cur = buf[s & 1];
        float*       __restrict__ nxt = buf[(s & 1) ^ 1];
        // useful rows [17-Tl+s, 46+Tl-s]; strip granular
        int lo = 14 - Tl + s;                    // 4rg >= lo
        int rgLo = (lo <= 0) ? 0 : ((lo + 3) >> 2);
        int rgHi = (46 + Tl - s) >> 2;           // <= 15 for Tl<=16
        if (rg >= rgLo && rg <= rgHi) {          // wave-uniform branch
            // issue boundary reads first ...
            float up0 = cur[rm1*TS + lane];
            float dnL = cur[rp4*TS + lane];
            // ... then pair B (rows 1,2): LDS-free, hides the read latency
            v2f upB = {pmA.x, pmB.x};            // {mu0, mu1}
            v2f dnB = {pmB.y, pmA.y};            // {mu2, mu3}
            v2f lfB = {dpp_shr1(pmB.x), dpp_shr1(pmB.y)};
            v2f rtB = {dpp_shl1(pmB.x), dpp_shl1(pmB.y)};
            v2f e = pk_fma(KxB, pmB, KyB);
            e = pk_fma(KzB, dnB, e);
            e = pk_fma(KwB, rtB, e);
            e = pk_fma(K2xB, upB, e);
            e = pk_fma(K2yB, lfB, e);
            pvB = pk_fma(pvB, C07, pk_mul(C001, e));
            v2f nmB = pk_clamp(pk_add(pmB, pvB));
            // pair A (rows 0,3): needs up0/dnL; produces boundary rows
            v2f upA = {up0,   pmB.y};            // {up(row0), mu2}
            v2f dnA = {pmB.x, dnL};              // {mu1, dn(row3)}
            v2f lfA = {dpp_shr1(pmA.x), dpp_shr1(pmA.y)};
            v2f rtA = {dpp_shl1(pmA.x), dpp_shl1(pmA.y)};
            v2f d = pk_fma(KxA, pmA, KyA);
            d = pk_fma(KzA, dnA, d);
            d = pk_fma(KwA, rtA, d);
            d = pk_fma(K2xA, upA, d);
            d = pk_fma(K2yA, lfA, d);
            pvA = pk_fma(pvA, C07, pk_mul(C001, d));
            v2f nmA = pk_clamp(pk_add(pmA, pvA));
            nxt[r0*TS + lane]       = nmA.x;     // boundary rows out
            nxt[(r0 + 3)*TS + lane] = nmA.y;
            pmA = nmA;
            pmB = nmB;
        }
        if (s + 1 < Tl) __syncthreads();   // last phase feeds registers only
    }

    // ---- store interior (rows [16,48), cols [16,48)) ----
    if (lane >= HALO && lane < HALO+32) {
        float muO[RPT] = {pmA.x, pmB.x, pmB.y, pmA.y};
        float vO_[RPT] = {pvA.x, pvB.x, pvB.y, pvA.y};
#pragma unroll
        for (int k = 0; k < RPT; ++k) {
            int r = r0 + k;
            if (r >= HALO && r < HALO+32) {
                if (mu_out) {
                    mu_out[gi[k]] = muO[k];  // final launch: only mu needed
                } else {
                    muvO[gi[k]] = make_float2(muO[k], vO_[k]);
                }
            }
        }
    }
}

// init packed muv plane {y, 0} + invariant coefficient plane
__global__ __launch_bounds__(256) void init_state_kernel(
    const float*  __restrict__ y,
    const float2* __restrict__ ew,
    const float2* __restrict__ uw,
    float2* muvA, float4* c1)
{
    int idx = blockIdx.x*256 + threadIdx.x;
    float2 e   = ew[idx];
    float2 uwv = uw[idx];
    float  yv  = y[idx];
    muvA[idx] = make_float2(yv, 0.f);
    c1[idx]   = make_float4(2.f*uwv.x, uwv.y*yv, e.x, e.y);
}

extern "C" void kernel_launch(void* const* d_in, const int* in_sizes, int n_in,
                              void* d_out, int out_size, void* d_ws, size_t ws_size,
                              hipStream_t stream) {
    const float* y  = (const float*)d_in[0];
    const float* ew = (const float*)d_in[1];
    const float* uw = (const float*)d_in[2];
    float* out = (float*)d_out;
    const int N = NPIX;

    // workspace: c1 (float4) + muvA, muvB (float2 planes) = 8 MB
    float4* c1   = (float4*)d_ws;
    float2* muvA = (float2*)(c1 + N);
    float2* muvB = muvA + N;

    hipLaunchKernelGGL(init_state_kernel, dim3(N/256), dim3(256), 0, stream,
                       y, (const float2*)ew, (const float2*)uw, muvA, c1);

    // balanced schedule: {15,15,14,14,14,14,14} = 100 iters, 7 launches
    static const int Tls[7] = {15, 15, 14, 14, 14, 14, 14};
    float2 *muvI = muvA, *muvO = muvB;
    for (int l = 0; l < 7; ++l) {
        float* mo = (l == 6) ? out : nullptr;
        hipLaunchKernelGGL(tile_kernel, dim3(8, 8, 4), dim3(NTHR), 0, stream,
                           muvI, muvO, c1, mo, Tls[l], (l == 0) ? 1 : 0);
        float2* t = muvI; muvI = muvO; muvO = t;
    }
}

// Round 15
// 138.441 us; speedup vs baseline: 1.0333x; 1.0166x over previous
//
#include <hip/hip_runtime.h>
#include <math.h>

// B=4, H=256, W=256, 100 iters. Closed-form mu-only update (sigma/rou are
// dead code for the mu output):
//   dmu = 2*uw1*mu + uw2*y + ew0*dn + ew1*rt + ew0_up*up + ew1_lf*lf
// Round 23: restore r12 (133.5us — best). r13/r14 bundles both regressed:
// r13 init-fold bloated the load path; r14's pair-B-first reorder put the
// boundary-row LDS write at the END of the phase, lengthening the
// barrier-to-barrier critical path (r10: path-bound, not barrier-count-
// bound). r12's order — pair A first, boundary rows written EARLY, pair B's
// VALU filling the post-write shadow — is the right schedule.
// Single provably-identical cleanup: `first` branch removed (init writes
// v=0 into muvA; every muvB px is written by launch 0 before launch 1
// reads it — interiors tile the grid).
// Structure: 64x64 tile, halo 16, lane=col, wave=4-row strip; DPP lateral
// neighbors (VALU pipe); LDS holds only strip-boundary rows (4 b32/iter);
// packed v_pk_{fma,mul,add}_f32 on pairs (0,3)+(1,2) (gfx950 has no
// pk_max/min -> scalar med3 clamp); strip row gate [17-Tl+s, 46+Tl-s];
// schedule {16x6, 4}; last barrier of each launch skipped.
// Budget: 7 x ~6us/launch all-in (launch floor: RPT=4 unique 256-block
// geometry, T<=16 col-halo cap) + ~28us pk-VALU + ~30us barrier chain +
// ~4us prolog. HBM <1%, conflicts 0, VALU already 2-wide packed.
#define NPIX  262144
#define TILE  64
#define TS    65             // padded LDS row stride (floats)
#define RPT   4
#define NSTRIP 16            // 16 strips x 4 rows
#define NTHR  1024
#define HALO  16

typedef float v2f __attribute__((ext_vector_type(2)));

__device__ __forceinline__ v2f pk_fma(v2f a, v2f b, v2f c) {
    v2f d;
    asm("v_pk_fma_f32 %0, %1, %2, %3" : "=v"(d) : "v"(a), "v"(b), "v"(c));
    return d;
}
__device__ __forceinline__ v2f pk_mul(v2f a, v2f b) {
    v2f d;
    asm("v_pk_mul_f32 %0, %1, %2" : "=v"(d) : "v"(a), "v"(b));
    return d;
}
__device__ __forceinline__ v2f pk_add(v2f a, v2f b) {
    v2f d;
    asm("v_pk_add_f32 %0, %1, %2" : "=v"(d) : "v"(a), "v"(b));
    return d;
}
__device__ __forceinline__ v2f pk_clamp(v2f a) {   // no pk_max/min on gfx950
    v2f d;
    d.x = fminf(fmaxf(a.x, 0.f), 63.f);   // -> v_med3_f32
    d.y = fminf(fmaxf(a.y, 0.f), 63.f);
    return d;
}
// wave-wide lateral shifts on the VALU pipe (gfx9 DPP, valid on CDNA)
__device__ __forceinline__ float dpp_shr1(float x) {   // lane l <- lane l-1
    int i = __builtin_amdgcn_update_dpp(0, __float_as_int(x),
                                        0x138, 0xf, 0xf, false);
    return __int_as_float(i);
}
__device__ __forceinline__ float dpp_shl1(float x) {   // lane l <- lane l+1
    int i = __builtin_amdgcn_update_dpp(0, __float_as_int(x),
                                        0x130, 0xf, 0xf, false);
    return __int_as_float(i);
}

// c1 = {2*uw1, uw2*y, ew0(down-edge), ew1(right-edge)}.
__global__ __launch_bounds__(NTHR) void tile_kernel(
    const float2* __restrict__ muvI, float2* __restrict__ muvO,
    const float4* __restrict__ c1,
    float* __restrict__ mu_out,   // non-null on last launch (muv not stored)
    int Tl)                       // iterations this launch (16 or 4)
{
    __shared__ float buf[2][TILE*TS];   // 33.3 KB

    int tid  = threadIdx.x;
    int rg   = tid >> 6;          // wave index == strip index (rows 4rg..+3)
    int lane = tid & 63;          // == tile col
    int bz = blockIdx.z;
    int h0 = blockIdx.y * 32;
    int w0 = blockIdx.x * 32;
    int w  = (w0 + lane - HALO) & 255;
    int r0 = RPT*rg;

    float mu[RPT], v[RPT];
    float4 k1[RPT];
    int gi[RPT];

    // ---- load (fully coalesced): muv b64, c1 b128 ----
#pragma unroll
    for (int k = 0; k < RPT; ++k) {
        int h = (h0 + r0 + k - HALO) & 255;
        gi[k] = (bz << 16) | (h << 8) | w;
        float2 s = muvI[gi[k]];
        mu[k] = s.x;
        v[k]  = s.y;
        k1[k] = c1[gi[k]];
    }
    float k2x0;
    {
        int hu = (h0 + ((rg == 0) ? 0 : r0-1) - HALO) & 255;
        k2x0 = c1[(bz << 16) | (hu << 8) | w].z;   // up-nb ew0 for row 0
    }

    // ---- pack state + coefficients: pair A = rows (0,3), B = rows (1,2) ----
    v2f pmA = {mu[0], mu[3]}, pmB = {mu[1], mu[2]};
    v2f pvA = {v[0],  v[3]},  pvB = {v[1],  v[2]};
    v2f KxA = {k1[0].x, k1[3].x}, KxB = {k1[1].x, k1[2].x};
    v2f KyA = {k1[0].y, k1[3].y}, KyB = {k1[1].y, k1[2].y};
    v2f KzA = {k1[0].z, k1[3].z}, KzB = {k1[1].z, k1[2].z};
    v2f KwA = {k1[0].w, k1[3].w}, KwB = {k1[1].w, k1[2].w};
    v2f K2xA = {k2x0,    k1[2].z}, K2xB = {k1[0].z, k1[1].z};
    v2f K2yA = {dpp_shr1(k1[0].w), dpp_shr1(k1[3].w)};
    v2f K2yB = {dpp_shr1(k1[1].w), dpp_shr1(k1[2].w)};
    const v2f C07  = {0.7f, 0.7f};
    const v2f C001 = {0.01f, 0.01f};

    // stage only strip-boundary rows (the only LDS-read rows)
    buf[0][r0*TS + lane]       = pmA.x;
    buf[0][(r0 + 3)*TS + lane] = pmA.y;
    __syncthreads();

    int rm1 = (rg == 0)        ? 0      : r0-1;
    int rp4 = (rg == NSTRIP-1) ? TILE-1 : r0+4;

    // ---- Tl fused Jacobi iterations, one barrier each, strip row gate ----
    for (int s = 0; s < Tl; ++s) {
        const float* __restrict__ cur = buf[s & 1];
        float*       __restrict__ nxt = buf[(s & 1) ^ 1];
        // useful rows [17-Tl+s, 46+Tl-s]; strip granular
        int lo = 14 - Tl + s;                    // 4rg >= lo
        int rgLo = (lo <= 0) ? 0 : ((lo + 3) >> 2);
        int rgHi = (46 + Tl - s) >> 2;           // <= 15 for Tl<=16
        if (rg >= rgLo && rg <= rgHi) {          // wave-uniform branch
            float up0 = cur[rm1*TS + lane];
            float dnL = cur[rp4*TS + lane];
            // pair A (rows 0,3): produces next phase's boundary rows
            v2f upA = {up0,   pmB.y};            // {up(row0), mu2}
            v2f dnA = {pmB.x, dnL};              // {mu1, dn(row3)}
            v2f lfA = {dpp_shr1(pmA.x), dpp_shr1(pmA.y)};
            v2f rtA = {dpp_shl1(pmA.x), dpp_shl1(pmA.y)};
            v2f d = pk_fma(KxA, pmA, KyA);
            d = pk_fma(KzA, dnA, d);
            d = pk_fma(KwA, rtA, d);
            d = pk_fma(K2xA, upA, d);
            d = pk_fma(K2yA, lfA, d);
            pvA = pk_fma(pvA, C07, pk_mul(C001, d));
            v2f nmA = pk_clamp(pk_add(pmA, pvA));
            nxt[r0*TS + lane]       = nmA.x;     // boundary rows out ASAP
            nxt[(r0 + 3)*TS + lane] = nmA.y;
            // pair B (rows 1,2): pure register (old pmA/pmB still live)
            v2f upB = {pmA.x, pmB.x};            // {mu0, mu1}
            v2f dnB = {pmB.y, pmA.y};            // {mu2, mu3}
            v2f lfB = {dpp_shr1(pmB.x), dpp_shr1(pmB.y)};
            v2f rtB = {dpp_shl1(pmB.x), dpp_shl1(pmB.y)};
            v2f e = pk_fma(KxB, pmB, KyB);
            e = pk_fma(KzB, dnB, e);
            e = pk_fma(KwB, rtB, e);
            e = pk_fma(K2xB, upB, e);
            e = pk_fma(K2yB, lfB, e);
            pvB = pk_fma(pvB, C07, pk_mul(C001, e));
            v2f nmB = pk_clamp(pk_add(pmB, pvB));
            pmA = nmA;
            pmB = nmB;
        }
        if (s + 1 < Tl) __syncthreads();   // last phase feeds registers only
    }

    // ---- store interior (rows [16,48), cols [16,48)) ----
    if (lane >= HALO && lane < HALO+32) {
        float muO[RPT] = {pmA.x, pmB.x, pmB.y, pmA.y};
        float vO_[RPT] = {pvA.x, pvB.x, pvB.y, pvA.y};
#pragma unroll
        for (int k = 0; k < RPT; ++k) {
            int r = r0 + k;
            if (r >= HALO && r < HALO+32) {
                if (mu_out) {
                    mu_out[gi[k]] = muO[k];  // final launch: only mu needed
                } else {
                    muvO[gi[k]] = make_float2(muO[k], vO_[k]);
                }
            }
        }
    }
}

// init packed muv plane {y, 0} + invariant coefficient plane
__global__ __launch_bounds__(256) void init_state_kernel(
    const float*  __restrict__ y,
    const float2* __restrict__ ew,
    const float2* __restrict__ uw,
    float2* muvA, float4* c1)
{
    int idx = blockIdx.x*256 + threadIdx.x;
    float2 e   = ew[idx];
    float2 uwv = uw[idx];
    float  yv  = y[idx];
    muvA[idx] = make_float2(yv, 0.f);
    c1[idx]   = make_float4(2.f*uwv.x, uwv.y*yv, e.x, e.y);
}

extern "C" void kernel_launch(void* const* d_in, const int* in_sizes, int n_in,
                              void* d_out, int out_size, void* d_ws, size_t ws_size,
                              hipStream_t stream) {
    const float* y  = (const float*)d_in[0];
    const float* ew = (const float*)d_in[1];
    const float* uw = (const float*)d_in[2];
    float* out = (float*)d_out;
    const int N = NPIX;

    // workspace: c1 (float4) + muvA, muvB (float2 planes) = 8 MB
    float4* c1   = (float4*)d_ws;
    float2* muvA = (float2*)(c1 + N);
    float2* muvB = muvA + N;

    hipLaunchKernelGGL(init_state_kernel, dim3(N/256), dim3(256), 0, stream,
                       y, (const float2*)ew, (const float2*)uw, muvA, c1);

    // 6 launches of 16 iters + final launch of 4 = 100
    static const int Tls[7] = {16, 16, 16, 16, 16, 16, 4};
    float2 *muvI = muvA, *muvO = muvB;
    for (int l = 0; l < 7; ++l) {
        float* mo = (l == 6) ? out : nullptr;
        hipLaunchKernelGGL(tile_kernel, dim3(8, 8, 4), dim3(NTHR), 0, stream,
                           muvI, muvO, c1, mo, Tls[l]);
        float2* t = muvI; muvI = muvO; muvO = t;
    }
}